// Round 2
// baseline (4747.130 us; speedup 1.0000x reference)
//
#include <hip/hip_runtime.h>
#include <hip/hip_bf16.h>
#include <math.h>

constexpr int NN = 50000;    // nodes
constexpr int NE = 600000;   // edges
constexpr int HD = 128;      // hidden
constexpr int NG = 512;      // graphs
constexpr float EPSV = 1e-5f;
constexpr float PI_F = 3.14159265358979323846f;

static __device__ __forceinline__ float wave_reduce(float v) {
#pragma unroll
  for (int off = 32; off > 0; off >>= 1) v += __shfl_xor(v, off, 64);
  return v;
}

// ---------------- CSR build ----------------
__global__ void deg_hist(const int* __restrict__ dst, int* __restrict__ deg) {
  int i = blockIdx.x * 256 + threadIdx.x;
  if (i < NE) atomicAdd(&deg[dst[i]], 1);
}

__global__ void scanA(const int* __restrict__ deg, int* __restrict__ part) {
  __shared__ int sh[256];
  int b = blockIdx.x, tid = threadIdx.x;
  int sum = 0;
  for (int k = tid; k < 1024; k += 256) {
    int idx = b * 1024 + k;
    if (idx < NN) sum += deg[idx];
  }
  sh[tid] = sum; __syncthreads();
  for (int s = 128; s; s >>= 1) { if (tid < s) sh[tid] += sh[tid + s]; __syncthreads(); }
  if (tid == 0) part[b] = sh[0];
}

__global__ void scanB(int* __restrict__ part, int nb) {
  if (threadIdx.x == 0) {
    int run = 0;
    for (int i = 0; i < nb; ++i) { int v = part[i]; part[i] = run; run += v; }
  }
}

__global__ void scanC(const int* __restrict__ deg, const int* __restrict__ part,
                      int* __restrict__ rowstart, int* __restrict__ cursor) {
  __shared__ int sh[256];
  int b = blockIdx.x, tid = threadIdx.x;
  int base = b * 1024 + tid * 4;
  int v[4];
#pragma unroll
  for (int k = 0; k < 4; ++k) v[k] = (base + k < NN) ? deg[base + k] : 0;
  int tot = v[0] + v[1] + v[2] + v[3];
  sh[tid] = tot; __syncthreads();
  for (int off = 1; off < 256; off <<= 1) {
    int x = (tid >= off) ? sh[tid - off] : 0;
    __syncthreads();
    sh[tid] += x;
    __syncthreads();
  }
  int excl = part[b] + sh[tid] - tot;
#pragma unroll
  for (int k = 0; k < 4; ++k) {
    if (base + k < NN) { rowstart[base + k] = excl; cursor[base + k] = excl; excl += v[k]; }
  }
}

__global__ void scatter_k(const int* __restrict__ src, const int* __restrict__ dst,
                          int* __restrict__ cursor, int* __restrict__ ceid, int* __restrict__ csrc) {
  int i = blockIdx.x * 256 + threadIdx.x;
  if (i < NE) {
    int d = dst[i];
    int pos = atomicAdd(&cursor[d], 1);
    ceid[pos] = i;
    csrc[pos] = src[i];
  }
}

// ---------------- self-loop attr (mean of incoming edge_attr) ----------------
__global__ void sloop_k(const float* __restrict__ eattr, const int* __restrict__ rowstart,
                        const int* __restrict__ deg, const int* __restrict__ ceid,
                        float* __restrict__ sloop) {
  int tid = threadIdx.x;
  int j = tid & 127, half = tid >> 7;
  int n = blockIdx.x * 2 + half;
  if (n >= NN) return;
  int st = rowstart[n], cnt = deg[n];
  float a = 0.f;
  for (int k = 0; k < cnt; ++k) {
    int e = ceid[st + k];
    a += eattr[(size_t)e * HD + j];
  }
  sloop[(size_t)n * HD + j] = a / (float)max(cnt, 1);
}

// ---------------- node GEMM: out = act(in @ W + b), optionally dual ----------------
template <int DUAL, int ACT>
__global__ __launch_bounds__(256) void node_gemm(
    const float* __restrict__ in, const float* __restrict__ W1, const float* __restrict__ b1,
    const float* __restrict__ W2, const float* __restrict__ b2,
    float* __restrict__ o1, float* __restrict__ o2) {
  __shared__ float xs[32][HD];
  const int tid = threadIdx.x;
  const int j = tid & 127;
  const int half = tid >> 7;
  const int r0 = blockIdx.x * 32;
  for (int k = tid; k < 32 * HD / 4; k += 256) {
    int r = k >> 5, c4 = k & 31;
    float4 v = make_float4(0.f, 0.f, 0.f, 0.f);
    if (r0 + r < NN) v = ((const float4*)(in + (size_t)(r0 + r) * HD))[c4];
    *((float4*)&xs[r][c4 * 4]) = v;
  }
  __syncthreads();
  float acc1[16], acc2[16];
  const float bb1 = b1[j];
#pragma unroll
  for (int k = 0; k < 16; ++k) acc1[k] = bb1;
  if (DUAL) {
    const float bb2 = b2[j];
#pragma unroll
    for (int k = 0; k < 16; ++k) acc2[k] = bb2;
  }
#pragma unroll 4
  for (int i = 0; i < HD; i += 4) {
    const float w10 = W1[(i + 0) * HD + j], w11 = W1[(i + 1) * HD + j];
    const float w12 = W1[(i + 2) * HD + j], w13 = W1[(i + 3) * HD + j];
    float w20 = 0.f, w21 = 0.f, w22 = 0.f, w23 = 0.f;
    if (DUAL) {
      w20 = W2[(i + 0) * HD + j]; w21 = W2[(i + 1) * HD + j];
      w22 = W2[(i + 2) * HD + j]; w23 = W2[(i + 3) * HD + j];
    }
#pragma unroll
    for (int k = 0; k < 16; ++k) {
      const float4 a = *(const float4*)&xs[half * 16 + k][i];
      acc1[k] = fmaf(a.x, w10, fmaf(a.y, w11, fmaf(a.z, w12, fmaf(a.w, w13, acc1[k]))));
      if (DUAL)
        acc2[k] = fmaf(a.x, w20, fmaf(a.y, w21, fmaf(a.z, w22, fmaf(a.w, w23, acc2[k]))));
    }
  }
#pragma unroll
  for (int k = 0; k < 16; ++k) {
    int r = r0 + half * 16 + k;
    if (r < NN) {
      float v1 = acc1[k];
      if (ACT) v1 = tanhf(v1);
      o1[(size_t)r * HD + j] = v1;
      if (DUAL) o2[(size_t)r * HD + j] = acc2[k];
    }
  }
}

// ---------------- per-edge attention logits ----------------
// ev[e] = att . leaky(xl[src]+xr[dst]+ea@We)
// One wave per 8-edge octet; lane l covers columns j=l and j=l+64.
// We in LDS (weight reads only on LDS pipe); ea rows read as wave-uniform
// float4 global loads (VMEM pipe); no staging, no syncthreads in hot loop.
__global__ __launch_bounds__(256, 2) void edge_scores(
    const float* __restrict__ eattr, const float* __restrict__ sloop,
    const int* __restrict__ src, const int* __restrict__ dst,
    const float* __restrict__ xl, const float* __restrict__ xr,
    const float* __restrict__ We, const float* __restrict__ att,
    float* __restrict__ ev) {
  __shared__ float We_s[HD * HD];      // 64 KB
  const int tid = threadIdx.x;
  const int l = tid & 63;              // lane
  const int wv = tid >> 6;             // wave 0..3
  for (int k = tid; k < HD * HD / 4; k += 256)
    ((float4*)We_s)[k] = ((const float4*)We)[k];
  __syncthreads();
  const float att_lo = att[l];
  const float att_hi = att[l + 64];
  const int total = NE + NN;
  const int stride = gridDim.x * 32;   // 4 waves/block * 8 edges
  for (int base = (blockIdx.x * 4 + wv) * 8; base < total; base += stride) {
    const float* rowp[8];
    float acc[8][2];
#pragma unroll
    for (int k = 0; k < 8; ++k) {
      const int e = base + k;
      if (e < total) {
        int s_, d_;
        if (e < NE) {
          s_ = src[e]; d_ = dst[e];
          rowp[k] = eattr + (size_t)e * HD;
        } else {
          s_ = d_ = e - NE;
          rowp[k] = sloop + (size_t)(e - NE) * HD;
        }
        acc[k][0] = xl[(size_t)s_ * HD + l] + xr[(size_t)d_ * HD + l];
        acc[k][1] = xl[(size_t)s_ * HD + l + 64] + xr[(size_t)d_ * HD + l + 64];
      } else {
        rowp[k] = eattr;               // safe dummy, result discarded
        acc[k][0] = 0.f; acc[k][1] = 0.f;
      }
    }
#pragma unroll 8
    for (int i = 0; i < HD; i += 4) {
      const float w0 = We_s[(i + 0) * HD + l];
      const float w1 = We_s[(i + 1) * HD + l];
      const float w2 = We_s[(i + 2) * HD + l];
      const float w3 = We_s[(i + 3) * HD + l];
      const float w4 = We_s[(i + 0) * HD + l + 64];
      const float w5 = We_s[(i + 1) * HD + l + 64];
      const float w6 = We_s[(i + 2) * HD + l + 64];
      const float w7 = We_s[(i + 3) * HD + l + 64];
#pragma unroll
      for (int k = 0; k < 8; ++k) {
        const float4 a = *(const float4*)(rowp[k] + i);   // wave-uniform
        acc[k][0] = fmaf(a.x, w0, fmaf(a.y, w1, fmaf(a.z, w2, fmaf(a.w, w3, acc[k][0]))));
        acc[k][1] = fmaf(a.x, w4, fmaf(a.y, w5, fmaf(a.z, w6, fmaf(a.w, w7, acc[k][1]))));
      }
    }
#pragma unroll
    for (int k = 0; k < 8; ++k) {
      float m0 = acc[k][0], m1 = acc[k][1];
      m0 = m0 > 0.f ? m0 : 0.2f * m0;
      m1 = m1 > 0.f ? m1 : 0.2f * m1;
      const float p = wave_reduce(fmaf(m0, att_lo, m1 * att_hi));
      const int e = base + k;
      if (l == 0 && e < total) ev[e] = p;
    }
  }
}

// ---------------- per-node softmax-aggregate: h[n] = sum alpha_e * xl[src_e] + cb ----------------
__global__ void aggregate(const float* __restrict__ xl, const float* __restrict__ evals,
                          const int* __restrict__ rowstart, const int* __restrict__ deg,
                          const int* __restrict__ ceid, const int* __restrict__ csrc,
                          const float* __restrict__ cb, float* __restrict__ hout) {
  int tid = threadIdx.x;
  int j = tid & 127, half = tid >> 7;
  int n = blockIdx.x * 2 + half;
  if (n >= NN) return;
  int st = rowstart[n], cnt = deg[n];
  // init with self-loop (edge id NE+n, feature row xl[n])
  float m = evals[NE + n];
  float s = 1.f;
  float p = xl[(size_t)n * HD + j];
  for (int k = 0; k < cnt; ++k) {
    int e = ceid[st + k];
    int sc = csrc[st + k];
    float evv = evals[e];
    float x = xl[(size_t)sc * HD + j];
    float nm = fmaxf(m, evv);
    float c = __expf(m - nm);
    float w = __expf(evv - nm);
    s = s * c + w;
    p = p * c + w * x;
    m = nm;
  }
  hout[(size_t)n * HD + j] = p / s + cb[j];
}

// ---------------- batchnorm stats / finalize / apply+tanh ----------------
__global__ void colstats(const float* __restrict__ h, float* __restrict__ cs, float* __restrict__ csq) {
  __shared__ float s1[256], s2[256];
  int tid = threadIdx.x;
  int j = tid & 127, half = tid >> 7;
  int rbeg = blockIdx.x * 256, rend = min(NN, rbeg + 256);
  float a = 0.f, b = 0.f;
  for (int r = rbeg + half; r < rend; r += 2) {
    float v = h[(size_t)r * HD + j];
    a += v; b += v * v;
  }
  s1[tid] = a; s2[tid] = b; __syncthreads();
  if (half == 0) {
    atomicAdd(&cs[j], s1[j] + s1[128 + j]);
    atomicAdd(&csq[j], s2[j] + s2[128 + j]);
  }
}

__global__ void bnfinal(const float* __restrict__ cs, const float* __restrict__ csq,
                        const float* __restrict__ g, const float* __restrict__ be,
                        float* __restrict__ scale, float* __restrict__ shift) {
  int j = threadIdx.x;
  float mu = cs[j] / (float)NN;
  float var = csq[j] / (float)NN - mu * mu;
  float sc = g[j] * rsqrtf(var + EPSV);
  scale[j] = sc;
  shift[j] = be[j] - mu * sc;
}

__global__ void bn_tanh(const float4* __restrict__ h, const float* __restrict__ scale,
                        const float* __restrict__ shift, float4* __restrict__ o) {
  const int n4 = NN * HD / 4;
  for (int i = blockIdx.x * blockDim.x + threadIdx.x; i < n4; i += gridDim.x * blockDim.x) {
    int c4 = i & 31;
    float4 v = h[i];
    float4 sc = ((const float4*)scale)[c4];
    float4 sh = ((const float4*)shift)[c4];
    float4 r;
    r.x = tanhf(fmaf(v.x, sc.x, sh.x));
    r.y = tanhf(fmaf(v.y, sc.y, sh.y));
    r.z = tanhf(fmaf(v.z, sc.z, sh.z));
    r.w = tanhf(fmaf(v.w, sc.w, sh.w));
    o[i] = r;
  }
}

// ---------------- graph ranges + attention pool + final ----------------
__global__ void ranges_k(const int* __restrict__ batch, int* __restrict__ gstart, int* __restrict__ gend) {
  int i = blockIdx.x * 256 + threadIdx.x;
  if (i < NN) {
    int b = batch[i];
    atomicMin(&gstart[b], i);
    atomicMax(&gend[b], i + 1);
  }
}

__global__ void pool_k(const float* __restrict__ gate, const float* __restrict__ xin,
                       const int* __restrict__ gstart, const int* __restrict__ gend,
                       float* __restrict__ pooled) {
  const int g = blockIdx.x, j = threadIdx.x;
  const int st = gstart[g];
  if (st == 0x7f7f7f7f) { pooled[(size_t)g * HD + j] = 0.f; return; }
  const int en = gend[g];
  float m = -INFINITY, s = 0.f, p = 0.f;
  for (int n = st; n < en; ++n) {
    const float gv = gate[(size_t)n * HD + j];
    const float hv = xin[(size_t)n * HD + j];
    const float nm = fmaxf(m, gv);
    const float c = __expf(m - nm);
    const float w = __expf(gv - nm);
    s = s * c + w;
    p = p * c + w * hv;
    m = nm;
  }
  pooled[(size_t)g * HD + j] = p / fmaxf(s, 1e-16f);
}

__global__ void final_k(const float* __restrict__ pooled, const float* __restrict__ Wf,
                        const float* __restrict__ bf, float* __restrict__ out) {
  __shared__ float ps[HD];
  const int g = blockIdx.x, j = threadIdx.x;
  ps[j] = pooled[(size_t)g * HD + j];
  __syncthreads();
  float acc = bf[j];
#pragma unroll 8
  for (int i = 0; i < HD; ++i) acc = fmaf(ps[i], Wf[i * HD + j], acc);
  out[(size_t)g * HD + j] = tanhf(acc) * PI_F;                   // axis
  out[(size_t)(NG + g) * HD + j] = 0.f;                          // aperture
}

extern "C" void kernel_launch(void* const* d_in, const int* in_sizes, int n_in,
                              void* d_out, int out_size, void* d_ws, size_t ws_size,
                              hipStream_t stream) {
  const float* x     = (const float*)d_in[0];
  const int*   eidx  = (const int*)d_in[1];
  const float* eattr = (const float*)d_in[2];
  const int*   batch = (const int*)d_in[3];
  const float *Wl1 = (const float*)d_in[4],  *bl1 = (const float*)d_in[5];
  const float *Wr1 = (const float*)d_in[6],  *br1 = (const float*)d_in[7];
  const float *We1 = (const float*)d_in[8],  *att1 = (const float*)d_in[9],  *cb1 = (const float*)d_in[10];
  const float *Wl2 = (const float*)d_in[11], *bl2 = (const float*)d_in[12];
  const float *Wr2 = (const float*)d_in[13], *br2 = (const float*)d_in[14];
  const float *We2 = (const float*)d_in[15], *att2 = (const float*)d_in[16], *cb2 = (const float*)d_in[17];
  const float *g1 = (const float*)d_in[18],  *be1 = (const float*)d_in[19];
  const float *g2 = (const float*)d_in[20],  *be2 = (const float*)d_in[21];
  const float *A1 = (const float*)d_in[22],  *a1 = (const float*)d_in[23];
  const float *A2 = (const float*)d_in[24],  *a2 = (const float*)d_in[25];
  const float *Wf = (const float*)d_in[26],  *bf = (const float*)d_in[27];
  const int* src = eidx;
  const int* dst = eidx + NE;

  float* ws = (float*)d_ws;
  const size_t NH = (size_t)NN * HD;
  float* sloopb = ws;
  float* xl     = ws + NH;
  float* xr     = ws + 2 * NH;
  float* hbuf   = ws + 3 * NH;
  float* hpr    = ws + 4 * NH;
  float* ev     = ws + 5 * NH;                 // NE+NN floats
  float* cs     = ev + (NE + NN);
  float* csq    = cs + HD;
  float* scale  = csq + HD;
  float* shift  = scale + HD;
  float* pooled = shift + HD;                  // NG*HD
  int* ideg     = (int*)(pooled + (size_t)NG * HD);
  int* rowstart = ideg + NN;
  int* cursor   = rowstart + NN;
  int* ceid     = cursor + NN;
  int* csrc     = ceid + NE;
  int* gstart   = csrc + NE;
  int* gend     = gstart + NG;
  int* part     = gend + NG;                   // 64 ints

  const int nbScan = (NN + 1023) / 1024;       // 49
  const int nbE = (NE + 255) / 256;            // 2344
  const int nbN = (NN + 255) / 256;            // 196

  // ---- CSR build (reused by both layers) ----
  hipMemsetAsync(ideg, 0, NN * sizeof(int), stream);
  hipMemsetAsync(gstart, 0x7f, NG * sizeof(int), stream);
  hipMemsetAsync(gend, 0, NG * sizeof(int), stream);
  deg_hist<<<nbE, 256, 0, stream>>>(dst, ideg);
  scanA<<<nbScan, 256, 0, stream>>>(ideg, part);
  scanB<<<1, 64, 0, stream>>>(part, nbScan);
  scanC<<<nbScan, 256, 0, stream>>>(ideg, part, rowstart, cursor);
  scatter_k<<<nbE, 256, 0, stream>>>(src, dst, cursor, ceid, csrc);
  sloop_k<<<NN / 2, 256, 0, stream>>>(eattr, rowstart, ideg, ceid, sloopb);

  // ---- layer 1 ----
  node_gemm<1, 0><<<(NN + 31) / 32, 256, 0, stream>>>(x, Wl1, bl1, Wr1, br1, xl, xr);
  edge_scores<<<512, 256, 0, stream>>>(eattr, sloopb, src, dst, xl, xr, We1, att1, ev);
  aggregate<<<NN / 2, 256, 0, stream>>>(xl, ev, rowstart, ideg, ceid, csrc, cb1, hbuf);
  hipMemsetAsync(cs, 0, 2 * HD * sizeof(float), stream);
  colstats<<<nbN, 256, 0, stream>>>(hbuf, cs, csq);
  bnfinal<<<1, 128, 0, stream>>>(cs, csq, g1, be1, scale, shift);
  bn_tanh<<<1024, 256, 0, stream>>>((const float4*)hbuf, scale, shift, (float4*)hpr);

  // ---- layer 2 ----
  node_gemm<1, 0><<<(NN + 31) / 32, 256, 0, stream>>>(hpr, Wl2, bl2, Wr2, br2, xl, xr);
  edge_scores<<<512, 256, 0, stream>>>(eattr, sloopb, src, dst, xl, xr, We2, att2, ev);
  aggregate<<<NN / 2, 256, 0, stream>>>(xl, ev, rowstart, ideg, ceid, csrc, cb2, hbuf);
  hipMemsetAsync(cs, 0, 2 * HD * sizeof(float), stream);
  colstats<<<nbN, 256, 0, stream>>>(hbuf, cs, csq);
  bnfinal<<<1, 128, 0, stream>>>(cs, csq, g2, be2, scale, shift);
  bn_tanh<<<1024, 256, 0, stream>>>((const float4*)hbuf, scale, shift, (float4*)hpr);

  // ---- attention pooling + final linear ----
  node_gemm<0, 1><<<(NN + 31) / 32, 256, 0, stream>>>(hpr, A1, a1, nullptr, nullptr, xr, nullptr);
  node_gemm<0, 0><<<(NN + 31) / 32, 256, 0, stream>>>(xr, A2, a2, nullptr, nullptr, xl, nullptr);
  ranges_k<<<nbN, 256, 0, stream>>>(batch, gstart, gend);
  pool_k<<<NG, 128, 0, stream>>>(xl, hpr, gstart, gend, pooled);
  final_k<<<NG, 128, 0, stream>>>(pooled, Wf, bf, (float*)d_out);
}

// Round 3
// 2164.272 us; speedup vs baseline: 2.1934x; 2.1934x over previous
//
#include <hip/hip_runtime.h>
#include <hip/hip_bf16.h>
#include <math.h>

constexpr int NN = 50000;    // nodes
constexpr int NE = 600000;   // edges
constexpr int HD = 128;      // hidden
constexpr int NG = 512;      // graphs
constexpr float EPSV = 1e-5f;
constexpr float PI_F = 3.14159265358979323846f;

static __device__ __forceinline__ float wave_reduce(float v) {
#pragma unroll
  for (int off = 32; off > 0; off >>= 1) v += __shfl_xor(v, off, 64);
  return v;
}

// ---------------- CSR build ----------------
__global__ void deg_hist(const int* __restrict__ dst, int* __restrict__ deg) {
  int i = blockIdx.x * 256 + threadIdx.x;
  if (i < NE) atomicAdd(&deg[dst[i]], 1);
}

__global__ void scanA(const int* __restrict__ deg, int* __restrict__ part) {
  __shared__ int sh[256];
  int b = blockIdx.x, tid = threadIdx.x;
  int sum = 0;
  for (int k = tid; k < 1024; k += 256) {
    int idx = b * 1024 + k;
    if (idx < NN) sum += deg[idx];
  }
  sh[tid] = sum; __syncthreads();
  for (int s = 128; s; s >>= 1) { if (tid < s) sh[tid] += sh[tid + s]; __syncthreads(); }
  if (tid == 0) part[b] = sh[0];
}

__global__ void scanB(int* __restrict__ part, int nb) {
  if (threadIdx.x == 0) {
    int run = 0;
    for (int i = 0; i < nb; ++i) { int v = part[i]; part[i] = run; run += v; }
  }
}

__global__ void scanC(const int* __restrict__ deg, const int* __restrict__ part,
                      int* __restrict__ rowstart, int* __restrict__ cursor) {
  __shared__ int sh[256];
  int b = blockIdx.x, tid = threadIdx.x;
  int base = b * 1024 + tid * 4;
  int v[4];
#pragma unroll
  for (int k = 0; k < 4; ++k) v[k] = (base + k < NN) ? deg[base + k] : 0;
  int tot = v[0] + v[1] + v[2] + v[3];
  sh[tid] = tot; __syncthreads();
  for (int off = 1; off < 256; off <<= 1) {
    int x = (tid >= off) ? sh[tid - off] : 0;
    __syncthreads();
    sh[tid] += x;
    __syncthreads();
  }
  int excl = part[b] + sh[tid] - tot;
#pragma unroll
  for (int k = 0; k < 4; ++k) {
    if (base + k < NN) { rowstart[base + k] = excl; cursor[base + k] = excl; excl += v[k]; }
  }
}

__global__ void scatter_k(const int* __restrict__ src, const int* __restrict__ dst,
                          int* __restrict__ cursor, int* __restrict__ ceid, int* __restrict__ csrc) {
  int i = blockIdx.x * 256 + threadIdx.x;
  if (i < NE) {
    int d = dst[i];
    int pos = atomicAdd(&cursor[d], 1);
    ceid[pos] = i;
    csrc[pos] = src[i];
  }
}

// ---------------- self-loop attr (mean of incoming edge_attr) ----------------
__global__ void sloop_k(const float* __restrict__ eattr, const int* __restrict__ rowstart,
                        const int* __restrict__ deg, const int* __restrict__ ceid,
                        float* __restrict__ sloop) {
  int tid = threadIdx.x;
  int j = tid & 127, half = tid >> 7;
  int n = blockIdx.x * 2 + half;
  if (n >= NN) return;
  int st = rowstart[n], cnt = deg[n];
  float a = 0.f;
  for (int k = 0; k < cnt; ++k) {
    int e = ceid[st + k];
    a += eattr[(size_t)e * HD + j];
  }
  sloop[(size_t)n * HD + j] = a / (float)max(cnt, 1);
}

// ---------------- node GEMM: out = act(in @ W + b), optionally dual ----------------
template <int DUAL, int ACT>
__global__ __launch_bounds__(256) void node_gemm(
    const float* __restrict__ in, const float* __restrict__ W1, const float* __restrict__ b1,
    const float* __restrict__ W2, const float* __restrict__ b2,
    float* __restrict__ o1, float* __restrict__ o2) {
  __shared__ float xs[32][HD];
  const int tid = threadIdx.x;
  const int j = tid & 127;
  const int half = tid >> 7;
  const int r0 = blockIdx.x * 32;
  for (int k = tid; k < 32 * HD / 4; k += 256) {
    int r = k >> 5, c4 = k & 31;
    float4 v = make_float4(0.f, 0.f, 0.f, 0.f);
    if (r0 + r < NN) v = ((const float4*)(in + (size_t)(r0 + r) * HD))[c4];
    *((float4*)&xs[r][c4 * 4]) = v;
  }
  __syncthreads();
  float acc1[16], acc2[16];
  const float bb1 = b1[j];
#pragma unroll
  for (int k = 0; k < 16; ++k) acc1[k] = bb1;
  if (DUAL) {
    const float bb2 = b2[j];
#pragma unroll
    for (int k = 0; k < 16; ++k) acc2[k] = bb2;
  }
#pragma unroll 4
  for (int i = 0; i < HD; i += 4) {
    const float w10 = W1[(i + 0) * HD + j], w11 = W1[(i + 1) * HD + j];
    const float w12 = W1[(i + 2) * HD + j], w13 = W1[(i + 3) * HD + j];
    float w20 = 0.f, w21 = 0.f, w22 = 0.f, w23 = 0.f;
    if (DUAL) {
      w20 = W2[(i + 0) * HD + j]; w21 = W2[(i + 1) * HD + j];
      w22 = W2[(i + 2) * HD + j]; w23 = W2[(i + 3) * HD + j];
    }
#pragma unroll
    for (int k = 0; k < 16; ++k) {
      const float4 a = *(const float4*)&xs[half * 16 + k][i];
      acc1[k] = fmaf(a.x, w10, fmaf(a.y, w11, fmaf(a.z, w12, fmaf(a.w, w13, acc1[k]))));
      if (DUAL)
        acc2[k] = fmaf(a.x, w20, fmaf(a.y, w21, fmaf(a.z, w22, fmaf(a.w, w23, acc2[k]))));
    }
  }
#pragma unroll
  for (int k = 0; k < 16; ++k) {
    int r = r0 + half * 16 + k;
    if (r < NN) {
      float v1 = acc1[k];
      if (ACT) v1 = tanhf(v1);
      o1[(size_t)r * HD + j] = v1;
      if (DUAL) o2[(size_t)r * HD + j] = acc2[k];
    }
  }
}

// ---------------- per-edge attention logits (register-blocked GEMM) ----------------
// ev[e] = att . leaky(xl[src]+xr[dst]+ea@We)
// Tile: 64 edges x 128 cols, K=128. 512 threads (8 waves). Thread (teg=tid>>5,
// tc=tid&31) owns edges teg*4..+3, cols tc*4..+3 (acc 4x4).
// ea tile double-buffered in LDS via global_load_lds width-16; We row-major in
// LDS (conflict-free contiguous b128 reads); ea reads are wave-uniform broadcasts.
constexpr int ETOT = NE + NN;
constexpr int NTIL = (ETOT + 63) / 64;

static __device__ __forceinline__ void stage_ea(const float* __restrict__ eattr,
                                                const float* __restrict__ sloop,
                                                float* buf, int e0, int w, int lane) {
#pragma unroll
  for (int t = 0; t < 4; ++t) {
    const int rr = (w * 4 + t) * 2 + (lane >> 5);   // tile row 0..63
    const int e = e0 + rr;
    const float* gp;
    if (e < NE) gp = eattr + (size_t)e * HD + (lane & 31) * 4;
    else if (e < ETOT) gp = sloop + (size_t)(e - NE) * HD + (lane & 31) * 4;
    else gp = eattr + (lane & 31) * 4;              // dummy row, discarded
    __builtin_amdgcn_global_load_lds(
        (const __attribute__((address_space(1))) void*)gp,
        (__attribute__((address_space(3))) void*)(buf + (w * 4 + t) * 256),
        16, 0, 0);
  }
}

__global__ __launch_bounds__(512, 2) void edge_scores(
    const float* __restrict__ eattr, const float* __restrict__ sloop,
    const int* __restrict__ src, const int* __restrict__ dst,
    const float* __restrict__ xl, const float* __restrict__ xr,
    const float* __restrict__ We, const float* __restrict__ att,
    float* __restrict__ ev) {
  __shared__ float We_s[HD * HD];       // 64 KB, row-major [k][j]
  __shared__ float ea_s[2][64 * HD];    // 2 x 32 KB double buffer
  const int tid = threadIdx.x;
  const int tc = tid & 31;              // col group: cols tc*4..+3
  const int teg = tid >> 5;             // edge group 0..15: edges teg*4..+3
  const int w = tid >> 6;               // wave 0..7
  const int lane = tid & 63;

  for (int k = tid; k < HD * HD / 4; k += 512)
    ((float4*)We_s)[k] = ((const float4*)We)[k];
  const float4 attv = ((const float4*)att)[tc];

  int it = blockIdx.x;
  int cur = 0;
  if (it < NTIL) stage_ea(eattr, sloop, ea_s[0], it * 64, w, lane);

  for (; it < NTIL; it += gridDim.x) {
    asm volatile("s_waitcnt vmcnt(0)" ::: "memory");
    __syncthreads();                     // ea_s[cur] staged; prev reads of cur^1 done
    const int nxt = it + (int)gridDim.x;
    if (nxt < NTIL) stage_ea(eattr, sloop, ea_s[cur ^ 1], nxt * 64, w, lane);

    const float* ea = ea_s[cur];
    float acc[4][4];
#pragma unroll
    for (int m = 0; m < 4; ++m)
#pragma unroll
      for (int c = 0; c < 4; ++c) acc[m][c] = 0.f;

#pragma unroll 4
    for (int k0 = 0; k0 < HD; k0 += 4) {
      const float4 w0 = *(const float4*)&We_s[(k0 + 0) * HD + tc * 4];
      const float4 w1 = *(const float4*)&We_s[(k0 + 1) * HD + tc * 4];
      const float4 w2 = *(const float4*)&We_s[(k0 + 2) * HD + tc * 4];
      const float4 w3 = *(const float4*)&We_s[(k0 + 3) * HD + tc * 4];
#pragma unroll
      for (int m = 0; m < 4; ++m) {
        const float4 a = *(const float4*)&ea[(teg * 4 + m) * HD + k0];
        acc[m][0] = fmaf(a.x, w0.x, fmaf(a.y, w1.x, fmaf(a.z, w2.x, fmaf(a.w, w3.x, acc[m][0]))));
        acc[m][1] = fmaf(a.x, w0.y, fmaf(a.y, w1.y, fmaf(a.z, w2.y, fmaf(a.w, w3.y, acc[m][1]))));
        acc[m][2] = fmaf(a.x, w0.z, fmaf(a.y, w1.z, fmaf(a.z, w2.z, fmaf(a.w, w3.z, acc[m][2]))));
        acc[m][3] = fmaf(a.x, w0.w, fmaf(a.y, w1.w, fmaf(a.z, w2.w, fmaf(a.w, w3.w, acc[m][3]))));
      }
    }

    const int e0 = it * 64;
#pragma unroll
    for (int m = 0; m < 4; ++m) {
      const int e = e0 + teg * 4 + m;
      const bool valid = e < ETOT;
      int s_, d_;
      if (e < NE) { s_ = src[e]; d_ = dst[e]; }
      else if (valid) { s_ = d_ = e - NE; }
      else { s_ = d_ = 0; }
      const float4 xa = ((const float4*)(xl + (size_t)s_ * HD))[tc];
      const float4 xb = ((const float4*)(xr + (size_t)d_ * HD))[tc];
      float v0 = acc[m][0] + xa.x + xb.x; v0 = v0 > 0.f ? v0 : 0.2f * v0;
      float v1 = acc[m][1] + xa.y + xb.y; v1 = v1 > 0.f ? v1 : 0.2f * v1;
      float v2 = acc[m][2] + xa.z + xb.z; v2 = v2 > 0.f ? v2 : 0.2f * v2;
      float v3 = acc[m][3] + xa.w + xb.w; v3 = v3 > 0.f ? v3 : 0.2f * v3;
      float p = fmaf(v0, attv.x, fmaf(v1, attv.y, fmaf(v2, attv.z, v3 * attv.w)));
#pragma unroll
      for (int off = 1; off < 32; off <<= 1) p += __shfl_xor(p, off, 64);
      if (tc == 0 && valid) ev[e] = p;
    }
    cur ^= 1;
  }
}

// ---------------- per-node softmax-aggregate: h[n] = sum alpha_e * xl[src_e] + cb ----------------
__global__ void aggregate(const float* __restrict__ xl, const float* __restrict__ evals,
                          const int* __restrict__ rowstart, const int* __restrict__ deg,
                          const int* __restrict__ ceid, const int* __restrict__ csrc,
                          const float* __restrict__ cb, float* __restrict__ hout) {
  int tid = threadIdx.x;
  int j = tid & 127, half = tid >> 7;
  int n = blockIdx.x * 2 + half;
  if (n >= NN) return;
  int st = rowstart[n], cnt = deg[n];
  // init with self-loop (edge id NE+n, feature row xl[n])
  float m = evals[NE + n];
  float s = 1.f;
  float p = xl[(size_t)n * HD + j];
  for (int k = 0; k < cnt; ++k) {
    int e = ceid[st + k];
    int sc = csrc[st + k];
    float evv = evals[e];
    float x = xl[(size_t)sc * HD + j];
    float nm = fmaxf(m, evv);
    float c = __expf(m - nm);
    float w = __expf(evv - nm);
    s = s * c + w;
    p = p * c + w * x;
    m = nm;
  }
  hout[(size_t)n * HD + j] = p / s + cb[j];
}

// ---------------- batchnorm stats / finalize / apply+tanh ----------------
__global__ void colstats(const float* __restrict__ h, float* __restrict__ cs, float* __restrict__ csq) {
  __shared__ float s1[256], s2[256];
  int tid = threadIdx.x;
  int j = tid & 127, half = tid >> 7;
  int rbeg = blockIdx.x * 256, rend = min(NN, rbeg + 256);
  float a = 0.f, b = 0.f;
  for (int r = rbeg + half; r < rend; r += 2) {
    float v = h[(size_t)r * HD + j];
    a += v; b += v * v;
  }
  s1[tid] = a; s2[tid] = b; __syncthreads();
  if (half == 0) {
    atomicAdd(&cs[j], s1[j] + s1[128 + j]);
    atomicAdd(&csq[j], s2[j] + s2[128 + j]);
  }
}

__global__ void bnfinal(const float* __restrict__ cs, const float* __restrict__ csq,
                        const float* __restrict__ g, const float* __restrict__ be,
                        float* __restrict__ scale, float* __restrict__ shift) {
  int j = threadIdx.x;
  float mu = cs[j] / (float)NN;
  float var = csq[j] / (float)NN - mu * mu;
  float sc = g[j] * rsqrtf(var + EPSV);
  scale[j] = sc;
  shift[j] = be[j] - mu * sc;
}

__global__ void bn_tanh(const float4* __restrict__ h, const float* __restrict__ scale,
                        const float* __restrict__ shift, float4* __restrict__ o) {
  const int n4 = NN * HD / 4;
  for (int i = blockIdx.x * blockDim.x + threadIdx.x; i < n4; i += gridDim.x * blockDim.x) {
    int c4 = i & 31;
    float4 v = h[i];
    float4 sc = ((const float4*)scale)[c4];
    float4 sh = ((const float4*)shift)[c4];
    float4 r;
    r.x = tanhf(fmaf(v.x, sc.x, sh.x));
    r.y = tanhf(fmaf(v.y, sc.y, sh.y));
    r.z = tanhf(fmaf(v.z, sc.z, sh.z));
    r.w = tanhf(fmaf(v.w, sc.w, sh.w));
    o[i] = r;
  }
}

// ---------------- graph ranges + attention pool + final ----------------
__global__ void ranges_k(const int* __restrict__ batch, int* __restrict__ gstart, int* __restrict__ gend) {
  int i = blockIdx.x * 256 + threadIdx.x;
  if (i < NN) {
    int b = batch[i];
    atomicMin(&gstart[b], i);
    atomicMax(&gend[b], i + 1);
  }
}

__global__ void pool_k(const float* __restrict__ gate, const float* __restrict__ xin,
                       const int* __restrict__ gstart, const int* __restrict__ gend,
                       float* __restrict__ pooled) {
  const int g = blockIdx.x, j = threadIdx.x;
  const int st = gstart[g];
  if (st == 0x7f7f7f7f) { pooled[(size_t)g * HD + j] = 0.f; return; }
  const int en = gend[g];
  float m = -INFINITY, s = 0.f, p = 0.f;
  for (int n = st; n < en; ++n) {
    const float gv = gate[(size_t)n * HD + j];
    const float hv = xin[(size_t)n * HD + j];
    const float nm = fmaxf(m, gv);
    const float c = __expf(m - nm);
    const float w = __expf(gv - nm);
    s = s * c + w;
    p = p * c + w * hv;
    m = nm;
  }
  pooled[(size_t)g * HD + j] = p / fmaxf(s, 1e-16f);
}

__global__ void final_k(const float* __restrict__ pooled, const float* __restrict__ Wf,
                        const float* __restrict__ bf, float* __restrict__ out) {
  __shared__ float ps[HD];
  const int g = blockIdx.x, j = threadIdx.x;
  ps[j] = pooled[(size_t)g * HD + j];
  __syncthreads();
  float acc = bf[j];
#pragma unroll 8
  for (int i = 0; i < HD; ++i) acc = fmaf(ps[i], Wf[i * HD + j], acc);
  out[(size_t)g * HD + j] = tanhf(acc) * PI_F;                   // axis
  out[(size_t)(NG + g) * HD + j] = 0.f;                          // aperture
}

extern "C" void kernel_launch(void* const* d_in, const int* in_sizes, int n_in,
                              void* d_out, int out_size, void* d_ws, size_t ws_size,
                              hipStream_t stream) {
  const float* x     = (const float*)d_in[0];
  const int*   eidx  = (const int*)d_in[1];
  const float* eattr = (const float*)d_in[2];
  const int*   batch = (const int*)d_in[3];
  const float *Wl1 = (const float*)d_in[4],  *bl1 = (const float*)d_in[5];
  const float *Wr1 = (const float*)d_in[6],  *br1 = (const float*)d_in[7];
  const float *We1 = (const float*)d_in[8],  *att1 = (const float*)d_in[9],  *cb1 = (const float*)d_in[10];
  const float *Wl2 = (const float*)d_in[11], *bl2 = (const float*)d_in[12];
  const float *Wr2 = (const float*)d_in[13], *br2 = (const float*)d_in[14];
  const float *We2 = (const float*)d_in[15], *att2 = (const float*)d_in[16], *cb2 = (const float*)d_in[17];
  const float *g1 = (const float*)d_in[18],  *be1 = (const float*)d_in[19];
  const float *g2 = (const float*)d_in[20],  *be2 = (const float*)d_in[21];
  const float *A1 = (const float*)d_in[22],  *a1 = (const float*)d_in[23];
  const float *A2 = (const float*)d_in[24],  *a2 = (const float*)d_in[25];
  const float *Wf = (const float*)d_in[26],  *bf = (const float*)d_in[27];
  const int* src = eidx;
  const int* dst = eidx + NE;

  float* ws = (float*)d_ws;
  const size_t NH = (size_t)NN * HD;
  float* sloopb = ws;
  float* xl     = ws + NH;
  float* xr     = ws + 2 * NH;
  float* hbuf   = ws + 3 * NH;
  float* hpr    = ws + 4 * NH;
  float* ev     = ws + 5 * NH;                 // NE+NN floats
  float* cs     = ev + (NE + NN);
  float* csq    = cs + HD;
  float* scale  = csq + HD;
  float* shift  = scale + HD;
  float* pooled = shift + HD;                  // NG*HD
  int* ideg     = (int*)(pooled + (size_t)NG * HD);
  int* rowstart = ideg + NN;
  int* cursor   = rowstart + NN;
  int* ceid     = cursor + NN;
  int* csrc     = ceid + NE;
  int* gstart   = csrc + NE;
  int* gend     = gstart + NG;
  int* part     = gend + NG;                   // 64 ints

  const int nbScan = (NN + 1023) / 1024;       // 49
  const int nbE = (NE + 255) / 256;            // 2344
  const int nbN = (NN + 255) / 256;            // 196

  // ---- CSR build (reused by both layers) ----
  hipMemsetAsync(ideg, 0, NN * sizeof(int), stream);
  hipMemsetAsync(gstart, 0x7f, NG * sizeof(int), stream);
  hipMemsetAsync(gend, 0, NG * sizeof(int), stream);
  deg_hist<<<nbE, 256, 0, stream>>>(dst, ideg);
  scanA<<<nbScan, 256, 0, stream>>>(ideg, part);
  scanB<<<1, 64, 0, stream>>>(part, nbScan);
  scanC<<<nbScan, 256, 0, stream>>>(ideg, part, rowstart, cursor);
  scatter_k<<<nbE, 256, 0, stream>>>(src, dst, cursor, ceid, csrc);
  sloop_k<<<NN / 2, 256, 0, stream>>>(eattr, rowstart, ideg, ceid, sloopb);

  // ---- layer 1 ----
  node_gemm<1, 0><<<(NN + 31) / 32, 256, 0, stream>>>(x, Wl1, bl1, Wr1, br1, xl, xr);
  edge_scores<<<256, 512, 0, stream>>>(eattr, sloopb, src, dst, xl, xr, We1, att1, ev);
  aggregate<<<NN / 2, 256, 0, stream>>>(xl, ev, rowstart, ideg, ceid, csrc, cb1, hbuf);
  hipMemsetAsync(cs, 0, 2 * HD * sizeof(float), stream);
  colstats<<<nbN, 256, 0, stream>>>(hbuf, cs, csq);
  bnfinal<<<1, 128, 0, stream>>>(cs, csq, g1, be1, scale, shift);
  bn_tanh<<<1024, 256, 0, stream>>>((const float4*)hbuf, scale, shift, (float4*)hpr);

  // ---- layer 2 ----
  node_gemm<1, 0><<<(NN + 31) / 32, 256, 0, stream>>>(hpr, Wl2, bl2, Wr2, br2, xl, xr);
  edge_scores<<<256, 512, 0, stream>>>(eattr, sloopb, src, dst, xl, xr, We2, att2, ev);
  aggregate<<<NN / 2, 256, 0, stream>>>(xl, ev, rowstart, ideg, ceid, csrc, cb2, hbuf);
  hipMemsetAsync(cs, 0, 2 * HD * sizeof(float), stream);
  colstats<<<nbN, 256, 0, stream>>>(hbuf, cs, csq);
  bnfinal<<<1, 128, 0, stream>>>(cs, csq, g2, be2, scale, shift);
  bn_tanh<<<1024, 256, 0, stream>>>((const float4*)hbuf, scale, shift, (float4*)hpr);

  // ---- attention pooling + final linear ----
  node_gemm<0, 1><<<(NN + 31) / 32, 256, 0, stream>>>(hpr, A1, a1, nullptr, nullptr, xr, nullptr);
  node_gemm<0, 0><<<(NN + 31) / 32, 256, 0, stream>>>(xr, A2, a2, nullptr, nullptr, xl, nullptr);
  ranges_k<<<nbN, 256, 0, stream>>>(batch, gstart, gend);
  pool_k<<<NG, 128, 0, stream>>>(xl, hpr, gstart, gend, pooled);
  final_k<<<NG, 128, 0, stream>>>(pooled, Wf, bf, (float*)d_out);
}

// Round 4
// 1778.189 us; speedup vs baseline: 2.6696x; 1.2171x over previous
//
#include <hip/hip_runtime.h>
#include <hip/hip_bf16.h>
#include <math.h>

constexpr int NN = 50000;    // nodes
constexpr int NE = 600000;   // edges
constexpr int HD = 128;      // hidden
constexpr int NG = 512;      // graphs
constexpr float EPSV = 1e-5f;
constexpr float PI_F = 3.14159265358979323846f;

typedef short s16x8 __attribute__((ext_vector_type(8)));
typedef float f32x4 __attribute__((ext_vector_type(4)));

// ---------------- CSR build ----------------
__global__ void deg_hist(const int* __restrict__ dst, int* __restrict__ deg) {
  int i = blockIdx.x * 256 + threadIdx.x;
  if (i < NE) atomicAdd(&deg[dst[i]], 1);
}

__global__ void scanA(const int* __restrict__ deg, int* __restrict__ part) {
  __shared__ int sh[256];
  int b = blockIdx.x, tid = threadIdx.x;
  int sum = 0;
  for (int k = tid; k < 1024; k += 256) {
    int idx = b * 1024 + k;
    if (idx < NN) sum += deg[idx];
  }
  sh[tid] = sum; __syncthreads();
  for (int s = 128; s; s >>= 1) { if (tid < s) sh[tid] += sh[tid + s]; __syncthreads(); }
  if (tid == 0) part[b] = sh[0];
}

__global__ void scanB(int* __restrict__ part, int nb) {
  if (threadIdx.x == 0) {
    int run = 0;
    for (int i = 0; i < nb; ++i) { int v = part[i]; part[i] = run; run += v; }
  }
}

__global__ void scanC(const int* __restrict__ deg, const int* __restrict__ part,
                      int* __restrict__ rowstart, int* __restrict__ cursor) {
  __shared__ int sh[256];
  int b = blockIdx.x, tid = threadIdx.x;
  int base = b * 1024 + tid * 4;
  int v[4];
#pragma unroll
  for (int k = 0; k < 4; ++k) v[k] = (base + k < NN) ? deg[base + k] : 0;
  int tot = v[0] + v[1] + v[2] + v[3];
  sh[tid] = tot; __syncthreads();
  for (int off = 1; off < 256; off <<= 1) {
    int x = (tid >= off) ? sh[tid - off] : 0;
    __syncthreads();
    sh[tid] += x;
    __syncthreads();
  }
  int excl = part[b] + sh[tid] - tot;
#pragma unroll
  for (int k = 0; k < 4; ++k) {
    if (base + k < NN) { rowstart[base + k] = excl; cursor[base + k] = excl; excl += v[k]; }
  }
}

__global__ void scatter_k(const int* __restrict__ src, const int* __restrict__ dst,
                          int* __restrict__ cursor, int* __restrict__ ceid, int* __restrict__ csrc) {
  int i = blockIdx.x * 256 + threadIdx.x;
  if (i < NE) {
    int d = dst[i];
    int pos = atomicAdd(&cursor[d], 1);
    ceid[pos] = i;
    csrc[pos] = src[i];
  }
}

// ---------------- self-loop attr (mean of incoming edge_attr) ----------------
__global__ void sloop_k(const float* __restrict__ eattr, const int* __restrict__ rowstart,
                        const int* __restrict__ deg, const int* __restrict__ ceid,
                        float* __restrict__ sloop) {
  int tid = threadIdx.x;
  int j = tid & 127, half = tid >> 7;
  int n = blockIdx.x * 2 + half;
  if (n >= NN) return;
  int st = rowstart[n], cnt = deg[n];
  float a = 0.f;
  for (int k = 0; k < cnt; ++k) {
    int e = ceid[st + k];
    a += eattr[(size_t)e * HD + j];
  }
  sloop[(size_t)n * HD + j] = a / (float)max(cnt, 1);
}

// ---------------- node GEMM: out = act(in @ W + b), optionally dual ----------------
template <int DUAL, int ACT>
__global__ __launch_bounds__(256) void node_gemm(
    const float* __restrict__ in, const float* __restrict__ W1, const float* __restrict__ b1,
    const float* __restrict__ W2, const float* __restrict__ b2,
    float* __restrict__ o1, float* __restrict__ o2) {
  __shared__ float xs[32][HD];
  const int tid = threadIdx.x;
  const int j = tid & 127;
  const int half = tid >> 7;
  const int r0 = blockIdx.x * 32;
  for (int k = tid; k < 32 * HD / 4; k += 256) {
    int r = k >> 5, c4 = k & 31;
    float4 v = make_float4(0.f, 0.f, 0.f, 0.f);
    if (r0 + r < NN) v = ((const float4*)(in + (size_t)(r0 + r) * HD))[c4];
    *((float4*)&xs[r][c4 * 4]) = v;
  }
  __syncthreads();
  float acc1[16], acc2[16];
  const float bb1 = b1[j];
#pragma unroll
  for (int k = 0; k < 16; ++k) acc1[k] = bb1;
  if (DUAL) {
    const float bb2 = b2[j];
#pragma unroll
    for (int k = 0; k < 16; ++k) acc2[k] = bb2;
  }
#pragma unroll 4
  for (int i = 0; i < HD; i += 4) {
    const float w10 = W1[(i + 0) * HD + j], w11 = W1[(i + 1) * HD + j];
    const float w12 = W1[(i + 2) * HD + j], w13 = W1[(i + 3) * HD + j];
    float w20 = 0.f, w21 = 0.f, w22 = 0.f, w23 = 0.f;
    if (DUAL) {
      w20 = W2[(i + 0) * HD + j]; w21 = W2[(i + 1) * HD + j];
      w22 = W2[(i + 2) * HD + j]; w23 = W2[(i + 3) * HD + j];
    }
#pragma unroll
    for (int k = 0; k < 16; ++k) {
      const float4 a = *(const float4*)&xs[half * 16 + k][i];
      acc1[k] = fmaf(a.x, w10, fmaf(a.y, w11, fmaf(a.z, w12, fmaf(a.w, w13, acc1[k]))));
      if (DUAL)
        acc2[k] = fmaf(a.x, w20, fmaf(a.y, w21, fmaf(a.z, w22, fmaf(a.w, w23, acc2[k]))));
    }
  }
#pragma unroll
  for (int k = 0; k < 16; ++k) {
    int r = r0 + half * 16 + k;
    if (r < NN) {
      float v1 = acc1[k];
      if (ACT) v1 = tanhf(v1);
      o1[(size_t)r * HD + j] = v1;
      if (DUAL) o2[(size_t)r * HD + j] = acc2[k];
    }
  }
}

// ---------------- per-edge attention logits (bf16x3 MFMA) ----------------
// ev[e] = att . leaky(xl[src]+xr[dst]+ea@We)
// Tile 128 edges x 128 cols. 8 waves: w = (ebg<<2)|cbg; ebg in {0,1} owns 64
// edges, cbg in {0..3} owns 32 cols. We (hi/lo bf16) lives in VGPRs per wave.
// ea (hi/lo bf16) in LDS, chunk-XOR swizzled for conflict-free A-frag reads.
// z tile round-trips through LDS for a coalesced epilogue.
constexpr int ETOT = NE + NN;
constexpr int NTIL2 = (ETOT + 127) / 128;

__device__ __forceinline__ void bf16split(float v, short& h, short& lo) {
  unsigned u = __float_as_uint(v);
  unsigned hu = (u + 0x7FFFu + ((u >> 16) & 1u)) & 0xFFFF0000u;
  float lof = v - __uint_as_float(hu);
  unsigned lu = __float_as_uint(lof);
  h = (short)(hu >> 16);
  lo = (short)((lu + 0x7FFFu + ((lu >> 16) & 1u)) >> 16);
}

__global__ __launch_bounds__(512, 2) void edge_scores(
    const float* __restrict__ eattr, const float* __restrict__ sloop,
    const int* __restrict__ src, const int* __restrict__ dst,
    const float* __restrict__ xl, const float* __restrict__ xr,
    const float* __restrict__ We, const float* __restrict__ att,
    float* __restrict__ ev) {
  __shared__ unsigned short eh_s[128 * 128];   // 32 KB  ea hi
  __shared__ unsigned short el_s[128 * 128];   // 32 KB  ea lo
  __shared__ float zbuf[128 * 128];            // 64 KB  z tile
  const int tid = threadIdx.x;
  const int l = tid & 63;
  const int w = tid >> 6;
  const int cbg = w & 3;
  const int ebg = w >> 2;
  const int l15 = l & 15;
  const int l16 = l >> 4;

  // ---- We hi/lo into registers: bh/bl[icb][kk]; col = cbg*32+icb*16+l15,
  //      k = kk*32 + 8*l16 + j  (B-frag: lane holds B[8*(l>>4)+j][l&15])
  s16x8 bh[2][4], bl[2][4];
#pragma unroll
  for (int icb = 0; icb < 2; ++icb) {
    const int c = cbg * 32 + icb * 16 + l15;
#pragma unroll
    for (int kk = 0; kk < 4; ++kk) {
#pragma unroll
      for (int j = 0; j < 8; ++j) {
        const int k = kk * 32 + 8 * l16 + j;
        short h_, lo_;
        bf16split(We[k * HD + c], h_, lo_);
        bh[icb][kk][j] = h_;
        bl[icb][kk][j] = lo_;
      }
    }
  }

  const int se = tid >> 2;   // staging: local edge 0..127
  const int kq = tid & 3;    // staging: k-quad (32 k)
  const int half = l >> 5;
  const int c4 = l & 31;
  const float4 attv = ((const float4*)att)[c4];

  float gl[32];
  int it = blockIdx.x;

  // prologue stage (tile it)
  if (it < NTIL2) {
    const int e = it * 128 + se;
    const float* rp = (e < NE) ? eattr + (size_t)e * HD
                   : (e < ETOT ? sloop + (size_t)(e - NE) * HD : eattr);
#pragma unroll
    for (int i = 0; i < 8; ++i) *(float4*)&gl[4 * i] = ((const float4*)(rp + kq * 32))[i];
#pragma unroll
    for (int i = 0; i < 4; ++i) {
      s16x8 vh, vl;
#pragma unroll
      for (int j = 0; j < 8; ++j) {
        short h_, lo_;
        bf16split(gl[8 * i + j], h_, lo_);
        vh[j] = h_; vl[j] = lo_;
      }
      const int chunk = (kq * 4 + i) ^ (se & 7);
      *(s16x8*)&eh_s[se * 128 + chunk * 8] = vh;
      *(s16x8*)&el_s[se * 128 + chunk * 8] = vl;
    }
  }

  for (; it < NTIL2; it += gridDim.x) {
    const int nxt = it + (int)gridDim.x;
    if (nxt < NTIL2) {   // issue next tile's global loads early (T14)
      const int e = nxt * 128 + se;
      const float* rp = (e < NE) ? eattr + (size_t)e * HD
                     : (e < ETOT ? sloop + (size_t)(e - NE) * HD : eattr);
#pragma unroll
      for (int i = 0; i < 8; ++i) *(float4*)&gl[4 * i] = ((const float4*)(rp + kq * 32))[i];
    }
    __syncthreads();   // staged ea visible

    // ---- MFMA: acc[ie][icb] = ea_tile @ We (bf16x3)
    f32x4 acc[4][2];
#pragma unroll
    for (int ie = 0; ie < 4; ++ie)
#pragma unroll
      for (int icb = 0; icb < 2; ++icb) acc[ie][icb] = (f32x4){0.f, 0.f, 0.f, 0.f};

#pragma unroll
    for (int kk = 0; kk < 4; ++kk) {
      s16x8 Ah[4], Al[4];
      const int chunk = ((kk * 4 + l16) ^ (l & 7)) * 8;
#pragma unroll
      for (int ie = 0; ie < 4; ++ie) {
        const int eloc = ebg * 64 + ie * 16 + l15;
        Ah[ie] = *(const s16x8*)&eh_s[eloc * 128 + chunk];
        Al[ie] = *(const s16x8*)&el_s[eloc * 128 + chunk];
      }
#pragma unroll
      for (int ie = 0; ie < 4; ++ie) {
#pragma unroll
        for (int icb = 0; icb < 2; ++icb) {
          acc[ie][icb] = __builtin_amdgcn_mfma_f32_16x16x32_bf16(Ah[ie], bh[icb][kk], acc[ie][icb], 0, 0, 0);
          acc[ie][icb] = __builtin_amdgcn_mfma_f32_16x16x32_bf16(Al[ie], bh[icb][kk], acc[ie][icb], 0, 0, 0);
          acc[ie][icb] = __builtin_amdgcn_mfma_f32_16x16x32_bf16(Ah[ie], bl[icb][kk], acc[ie][icb], 0, 0, 0);
        }
      }
    }

    // ---- z to LDS (C/D layout: col = l&15, row = (l>>4)*4 + r), col-swizzled
#pragma unroll
    for (int ie = 0; ie < 4; ++ie)
#pragma unroll
      for (int icb = 0; icb < 2; ++icb)
#pragma unroll
        for (int r = 0; r < 4; ++r) {
          const int eloc = ebg * 64 + ie * 16 + l16 * 4 + r;
          const int c = cbg * 32 + icb * 16 + l15;
          zbuf[eloc * 128 + (c ^ ((eloc & 7) << 2))] = acc[ie][icb][r];
        }
    __syncthreads();   // z visible

    // ---- epilogue: wave w handles edges w*16..w*16+15 (2 per iteration)
#pragma unroll
    for (int ii = 0; ii < 8; ++ii) {
      const int eloc = w * 16 + ii * 2 + half;
      const int e = it * 128 + eloc;
      const bool valid = e < ETOT;
      int s_ = 0, d_ = 0;
      if (e < NE) { s_ = src[e]; d_ = dst[e]; }
      else if (valid) { s_ = d_ = e - NE; }
      const float4 zv = *(const float4*)&zbuf[eloc * 128 + ((c4 ^ (eloc & 7)) << 2)];
      const float4 ga = ((const float4*)(xl + (size_t)s_ * HD))[c4];
      const float4 gb = ((const float4*)(xr + (size_t)d_ * HD))[c4];
      float m0 = zv.x + ga.x + gb.x; m0 = m0 > 0.f ? m0 : 0.2f * m0;
      float m1 = zv.y + ga.y + gb.y; m1 = m1 > 0.f ? m1 : 0.2f * m1;
      float m2 = zv.z + ga.z + gb.z; m2 = m2 > 0.f ? m2 : 0.2f * m2;
      float m3 = zv.w + ga.w + gb.w; m3 = m3 > 0.f ? m3 : 0.2f * m3;
      float p = fmaf(m0, attv.x, fmaf(m1, attv.y, fmaf(m2, attv.z, m3 * attv.w)));
#pragma unroll
      for (int off = 1; off < 32; off <<= 1) p += __shfl_xor(p, off, 64);
      if ((l & 31) == 0 && valid) ev[e] = p;
    }
    __syncthreads();   // all LDS reads done; safe to overwrite

    if (nxt < NTIL2) {   // convert + write next tile
#pragma unroll
      for (int i = 0; i < 4; ++i) {
        s16x8 vh, vl;
#pragma unroll
        for (int j = 0; j < 8; ++j) {
          short h_, lo_;
          bf16split(gl[8 * i + j], h_, lo_);
          vh[j] = h_; vl[j] = lo_;
        }
        const int chunk = (kq * 4 + i) ^ (se & 7);
        *(s16x8*)&eh_s[se * 128 + chunk * 8] = vh;
        *(s16x8*)&el_s[se * 128 + chunk * 8] = vl;
      }
    }
  }
}

// ---------------- per-node softmax-aggregate: h[n] = sum alpha_e * xl[src_e] + cb ----------------
__global__ void aggregate(const float* __restrict__ xl, const float* __restrict__ evals,
                          const int* __restrict__ rowstart, const int* __restrict__ deg,
                          const int* __restrict__ ceid, const int* __restrict__ csrc,
                          const float* __restrict__ cb, float* __restrict__ hout) {
  int tid = threadIdx.x;
  int j = tid & 127, half = tid >> 7;
  int n = blockIdx.x * 2 + half;
  if (n >= NN) return;
  int st = rowstart[n], cnt = deg[n];
  // init with self-loop (edge id NE+n, feature row xl[n])
  float m = evals[NE + n];
  float s = 1.f;
  float p = xl[(size_t)n * HD + j];
  for (int k = 0; k < cnt; ++k) {
    int e = ceid[st + k];
    int sc = csrc[st + k];
    float evv = evals[e];
    float x = xl[(size_t)sc * HD + j];
    float nm = fmaxf(m, evv);
    float c = __expf(m - nm);
    float w = __expf(evv - nm);
    s = s * c + w;
    p = p * c + w * x;
    m = nm;
  }
  hout[(size_t)n * HD + j] = p / s + cb[j];
}

// ---------------- batchnorm stats / finalize / apply+tanh ----------------
__global__ void colstats(const float* __restrict__ h, float* __restrict__ cs, float* __restrict__ csq) {
  __shared__ float s1[256], s2[256];
  int tid = threadIdx.x;
  int j = tid & 127, half = tid >> 7;
  int rbeg = blockIdx.x * 256, rend = min(NN, rbeg + 256);
  float a = 0.f, b = 0.f;
  for (int r = rbeg + half; r < rend; r += 2) {
    float v = h[(size_t)r * HD + j];
    a += v; b += v * v;
  }
  s1[tid] = a; s2[tid] = b; __syncthreads();
  if (half == 0) {
    atomicAdd(&cs[j], s1[j] + s1[128 + j]);
    atomicAdd(&csq[j], s2[j] + s2[128 + j]);
  }
}

__global__ void bnfinal(const float* __restrict__ cs, const float* __restrict__ csq,
                        const float* __restrict__ g, const float* __restrict__ be,
                        float* __restrict__ scale, float* __restrict__ shift) {
  int j = threadIdx.x;
  float mu = cs[j] / (float)NN;
  float var = csq[j] / (float)NN - mu * mu;
  float sc = g[j] * rsqrtf(var + EPSV);
  scale[j] = sc;
  shift[j] = be[j] - mu * sc;
}

__global__ void bn_tanh(const float4* __restrict__ h, const float* __restrict__ scale,
                        const float* __restrict__ shift, float4* __restrict__ o) {
  const int n4 = NN * HD / 4;
  for (int i = blockIdx.x * blockDim.x + threadIdx.x; i < n4; i += gridDim.x * blockDim.x) {
    int c4 = i & 31;
    float4 v = h[i];
    float4 sc = ((const float4*)scale)[c4];
    float4 sh = ((const float4*)shift)[c4];
    float4 r;
    r.x = tanhf(fmaf(v.x, sc.x, sh.x));
    r.y = tanhf(fmaf(v.y, sc.y, sh.y));
    r.z = tanhf(fmaf(v.z, sc.z, sh.z));
    r.w = tanhf(fmaf(v.w, sc.w, sh.w));
    o[i] = r;
  }
}

// ---------------- graph ranges + attention pool + final ----------------
__global__ void ranges_k(const int* __restrict__ batch, int* __restrict__ gstart, int* __restrict__ gend) {
  int i = blockIdx.x * 256 + threadIdx.x;
  if (i < NN) {
    int b = batch[i];
    atomicMin(&gstart[b], i);
    atomicMax(&gend[b], i + 1);
  }
}

__global__ void pool_k(const float* __restrict__ gate, const float* __restrict__ xin,
                       const int* __restrict__ gstart, const int* __restrict__ gend,
                       float* __restrict__ pooled) {
  const int g = blockIdx.x, j = threadIdx.x;
  const int st = gstart[g];
  if (st == 0x7f7f7f7f) { pooled[(size_t)g * HD + j] = 0.f; return; }
  const int en = gend[g];
  float m = -INFINITY, s = 0.f, p = 0.f;
  for (int n = st; n < en; ++n) {
    const float gv = gate[(size_t)n * HD + j];
    const float hv = xin[(size_t)n * HD + j];
    const float nm = fmaxf(m, gv);
    const float c = __expf(m - nm);
    const float w = __expf(gv - nm);
    s = s * c + w;
    p = p * c + w * hv;
    m = nm;
  }
  pooled[(size_t)g * HD + j] = p / fmaxf(s, 1e-16f);
}

__global__ void final_k(const float* __restrict__ pooled, const float* __restrict__ Wf,
                        const float* __restrict__ bf, float* __restrict__ out) {
  __shared__ float ps[HD];
  const int g = blockIdx.x, j = threadIdx.x;
  ps[j] = pooled[(size_t)g * HD + j];
  __syncthreads();
  float acc = bf[j];
#pragma unroll 8
  for (int i = 0; i < HD; ++i) acc = fmaf(ps[i], Wf[i * HD + j], acc);
  out[(size_t)g * HD + j] = tanhf(acc) * PI_F;                   // axis
  out[(size_t)(NG + g) * HD + j] = 0.f;                          // aperture
}

extern "C" void kernel_launch(void* const* d_in, const int* in_sizes, int n_in,
                              void* d_out, int out_size, void* d_ws, size_t ws_size,
                              hipStream_t stream) {
  const float* x     = (const float*)d_in[0];
  const int*   eidx  = (const int*)d_in[1];
  const float* eattr = (const float*)d_in[2];
  const int*   batch = (const int*)d_in[3];
  const float *Wl1 = (const float*)d_in[4],  *bl1 = (const float*)d_in[5];
  const float *Wr1 = (const float*)d_in[6],  *br1 = (const float*)d_in[7];
  const float *We1 = (const float*)d_in[8],  *att1 = (const float*)d_in[9],  *cb1 = (const float*)d_in[10];
  const float *Wl2 = (const float*)d_in[11], *bl2 = (const float*)d_in[12];
  const float *Wr2 = (const float*)d_in[13], *br2 = (const float*)d_in[14];
  const float *We2 = (const float*)d_in[15], *att2 = (const float*)d_in[16], *cb2 = (const float*)d_in[17];
  const float *g1 = (const float*)d_in[18],  *be1 = (const float*)d_in[19];
  const float *g2 = (const float*)d_in[20],  *be2 = (const float*)d_in[21];
  const float *A1 = (const float*)d_in[22],  *a1 = (const float*)d_in[23];
  const float *A2 = (const float*)d_in[24],  *a2 = (const float*)d_in[25];
  const float *Wf = (const float*)d_in[26],  *bf = (const float*)d_in[27];
  const int* src = eidx;
  const int* dst = eidx + NE;

  float* ws = (float*)d_ws;
  const size_t NH = (size_t)NN * HD;
  float* sloopb = ws;
  float* xl     = ws + NH;
  float* xr     = ws + 2 * NH;
  float* hbuf   = ws + 3 * NH;
  float* hpr    = ws + 4 * NH;
  float* ev     = ws + 5 * NH;                 // NE+NN floats
  float* cs     = ev + (NE + NN);
  float* csq    = cs + HD;
  float* scale  = csq + HD;
  float* shift  = scale + HD;
  float* pooled = shift + HD;                  // NG*HD
  int* ideg     = (int*)(pooled + (size_t)NG * HD);
  int* rowstart = ideg + NN;
  int* cursor   = rowstart + NN;
  int* ceid     = cursor + NN;
  int* csrc     = ceid + NE;
  int* gstart   = csrc + NE;
  int* gend     = gstart + NG;
  int* part     = gend + NG;                   // 64 ints

  const int nbScan = (NN + 1023) / 1024;       // 49
  const int nbE = (NE + 255) / 256;            // 2344
  const int nbN = (NN + 255) / 256;            // 196

  // ---- CSR build (reused by both layers) ----
  hipMemsetAsync(ideg, 0, NN * sizeof(int), stream);
  hipMemsetAsync(gstart, 0x7f, NG * sizeof(int), stream);
  hipMemsetAsync(gend, 0, NG * sizeof(int), stream);
  deg_hist<<<nbE, 256, 0, stream>>>(dst, ideg);
  scanA<<<nbScan, 256, 0, stream>>>(ideg, part);
  scanB<<<1, 64, 0, stream>>>(part, nbScan);
  scanC<<<nbScan, 256, 0, stream>>>(ideg, part, rowstart, cursor);
  scatter_k<<<nbE, 256, 0, stream>>>(src, dst, cursor, ceid, csrc);
  sloop_k<<<NN / 2, 256, 0, stream>>>(eattr, rowstart, ideg, ceid, sloopb);

  // ---- layer 1 ----
  node_gemm<1, 0><<<(NN + 31) / 32, 256, 0, stream>>>(x, Wl1, bl1, Wr1, br1, xl, xr);
  edge_scores<<<256, 512, 0, stream>>>(eattr, sloopb, src, dst, xl, xr, We1, att1, ev);
  aggregate<<<NN / 2, 256, 0, stream>>>(xl, ev, rowstart, ideg, ceid, csrc, cb1, hbuf);
  hipMemsetAsync(cs, 0, 2 * HD * sizeof(float), stream);
  colstats<<<nbN, 256, 0, stream>>>(hbuf, cs, csq);
  bnfinal<<<1, 128, 0, stream>>>(cs, csq, g1, be1, scale, shift);
  bn_tanh<<<1024, 256, 0, stream>>>((const float4*)hbuf, scale, shift, (float4*)hpr);

  // ---- layer 2 ----
  node_gemm<1, 0><<<(NN + 31) / 32, 256, 0, stream>>>(hpr, Wl2, bl2, Wr2, br2, xl, xr);
  edge_scores<<<256, 512, 0, stream>>>(eattr, sloopb, src, dst, xl, xr, We2, att2, ev);
  aggregate<<<NN / 2, 256, 0, stream>>>(xl, ev, rowstart, ideg, ceid, csrc, cb2, hbuf);
  hipMemsetAsync(cs, 0, 2 * HD * sizeof(float), stream);
  colstats<<<nbN, 256, 0, stream>>>(hbuf, cs, csq);
  bnfinal<<<1, 128, 0, stream>>>(cs, csq, g2, be2, scale, shift);
  bn_tanh<<<1024, 256, 0, stream>>>((const float4*)hbuf, scale, shift, (float4*)hpr);

  // ---- attention pooling + final linear ----
  node_gemm<0, 1><<<(NN + 31) / 32, 256, 0, stream>>>(hpr, A1, a1, nullptr, nullptr, xr, nullptr);
  node_gemm<0, 0><<<(NN + 31) / 32, 256, 0, stream>>>(xr, A2, a2, nullptr, nullptr, xl, nullptr);
  ranges_k<<<nbN, 256, 0, stream>>>(batch, gstart, gend);
  pool_k<<<NG, 128, 0, stream>>>(xl, hpr, gstart, gend, pooled);
  final_k<<<NG, 128, 0, stream>>>(pooled, Wf, bf, (float*)d_out);
}